// Round 4
// baseline (386.444 us; speedup 1.0000x reference)
//
#include <hip/hip_runtime.h>
#include <hip/hip_bf16.h>
#include <stdint.h>

#define HID 2048
#define NHEAD 16
#define DHEAD 128
#define BB 2
#define SS 2048
#define MM (BB*SS)       // 4096
#define NQKV (3*HID)     // 6144

typedef __attribute__((ext_vector_type(8))) short bf16x8;
typedef __attribute__((ext_vector_type(4))) float f32x4;
typedef unsigned short ushort_t;

__device__ __forceinline__ f32x4 mfma16(bf16x8 a, bf16x8 b, f32x4 c) {
    return __builtin_amdgcn_mfma_f32_16x16x32_bf16(a, b, c, 0, 0, 0);
}

__device__ __forceinline__ float bf2f(ushort_t u) {
    unsigned int x = ((unsigned int)u) << 16;
    return __builtin_bit_cast(float, x);
}
__device__ __forceinline__ ushort_t f2bf(float f) {
    unsigned int x = __builtin_bit_cast(unsigned int, f);
    unsigned int r = (x + 0x7FFFu + ((x >> 16) & 1u)) >> 16;
    return (ushort_t)r;
}

__device__ __forceinline__ void cvt8(const float* __restrict__ g, ushort_t* l) {
    float4 a = *(const float4*)g;
    float4 b = *(const float4*)(g + 4);
    union { ushort_t u[8]; uint4 v; } t;
    t.u[0] = f2bf(a.x); t.u[1] = f2bf(a.y); t.u[2] = f2bf(a.z); t.u[3] = f2bf(a.w);
    t.u[4] = f2bf(b.x); t.u[5] = f2bf(b.y); t.u[6] = f2bf(b.z); t.u[7] = f2bf(b.w);
    *(uint4*)l = t.v;
}

// async global->LDS, 16 bytes per lane; LDS base wave-uniform, HW adds lane*16
__device__ __forceinline__ void gload16(const ushort_t* g, ushort_t* l) {
    __builtin_amdgcn_global_load_lds(
        (const __attribute__((address_space(1))) unsigned int*)(const void*)g,
        (__attribute__((address_space(3))) unsigned int*)(void*)l,
        16, 0, 0);
}

#define WAITV0 asm volatile("s_waitcnt vmcnt(0)" ::: "memory")
#define WAITV2 asm volatile("s_waitcnt vmcnt(2)" ::: "memory")
#define WAITV4 asm volatile("s_waitcnt vmcnt(4)" ::: "memory")
#define WAITV6 asm volatile("s_waitcnt vmcnt(6)" ::: "memory")
#define BAR()  __builtin_amdgcn_s_barrier()

// ---------------------------------------------------------------------------
// f32 -> bf16 bulk convert, all three tensors in one launch
// ---------------------------------------------------------------------------
__global__ void cvt3_kernel(const float* __restrict__ a, ushort_t* __restrict__ da, int na,
                            const float* __restrict__ b, ushort_t* __restrict__ db, int nb,
                            const float* __restrict__ c, ushort_t* __restrict__ dc, int nc)
{
    int i = blockIdx.x * blockDim.x + threadIdx.x;
    if (i < na) {
        cvt8(a + (size_t)i * 8, da + (size_t)i * 8);
    } else if (i < na + nb) {
        int j = i - na;
        cvt8(b + (size_t)j * 8, db + (size_t)j * 8);
    } else if (i < na + nb + nc) {
        int j = i - na - nb;
        cvt8(c + (size_t)j * 8, dc + (size_t)j * 8);
    }
}

// ---------------------------------------------------------------------------
// QKV GEMM (round-1 proven core): BM=256, BN=128, BK=64, 512 thr = 8 waves,
// 3 rotating LDS buffers, counted vmcnt(6), T2 swizzle, T5 setprio.
// For V blocks (n0 >= 4096) MFMA operands SWAPPED so acc holds C^T.
// ---------------------------------------------------------------------------
#define BM 256
#define BN 128
#define BKK 64
#define NTK (HID/BKK)         // 32
#define ASZ (BM*BKK)          // 16384 ushorts (32 KiB)
#define BSZ (BN*BKK)          // 8192 ushorts (16 KiB)
#define BUFSZ (ASZ+BSZ)       // 24576 ushorts (48 KiB)

__global__ __launch_bounds__(512, 1) void qkv_gemm_fast(
    const ushort_t* __restrict__ X,
    const ushort_t* __restrict__ W,
    const float* __restrict__ bias,
    ushort_t* __restrict__ qws,
    ushort_t* __restrict__ kws,
    ushort_t* __restrict__ vtws)
{
    __shared__ __align__(16) ushort_t smem[3 * BUFSZ];   // 144 KiB

    const int tid  = threadIdx.x;
    const int lane = tid & 63;
    const int w    = tid >> 6;            // 0..7
    const int wm   = w >> 1, wn = w & 1;
    const int quad = lane >> 4;
    const int l15  = lane & 15;
    const int sub  = (lane & 7) ^ (lane >> 3);   // inverse-swizzled src chunk
    const int rloc = lane >> 3;                  // row within 8-row block
    const int m0 = blockIdx.y * BM;
    const int n0 = blockIdx.x * BN;
    const bool vmode = (n0 >= 2 * HID);

    const ushort_t* gA = X + (size_t)m0 * HID;
    const ushort_t* gB = W + (size_t)n0 * HID;

    f32x4 acc[4][4];
#pragma unroll
    for (int i = 0; i < 4; i++)
#pragma unroll
        for (int j = 0; j < 4; j++)
#pragma unroll
            for (int e = 0; e < 4; e++) acc[i][j][e] = 0.f;

    auto STAGE = [&](int bufi, int t) {
        ushort_t* lA = smem + bufi * BUFSZ;
        ushort_t* lB = lA + ASZ;
        const ushort_t* ga = gA + t * BKK;
        const ushort_t* gb = gB + t * BKK;
#pragma unroll
        for (int i = 0; i < 4; i++) {
            int blk = w * 4 + i;                 // 0..31 -> A rows blk*8..+7
            gload16(ga + (size_t)(blk * 8 + rloc) * HID + sub * 8, lA + blk * 512);
        }
#pragma unroll
        for (int i = 0; i < 2; i++) {
            int blk = w * 2 + i;                 // 0..15 -> B rows blk*8..+7
            gload16(gb + (size_t)(blk * 8 + rloc) * HID + sub * 8, lB + blk * 512);
        }
    };

    auto COMPUTE = [&](int bufi) {
        const ushort_t* lA = smem + bufi * BUFSZ;
        const ushort_t* lB = lA + ASZ;
        bf16x8 af[2][4], bfr[2][4];
#pragma unroll
        for (int kk = 0; kk < 2; kk++) {
            const int cs = ((kk * 4 + quad) ^ (l15 & 7)) << 3;   // swizzled chunk
#pragma unroll
            for (int mb = 0; mb < 4; mb++)
                af[kk][mb] = *(const bf16x8*)(lA + (wm * 64 + mb * 16 + l15) * 64 + cs);
#pragma unroll
            for (int nb = 0; nb < 4; nb++)
                bfr[kk][nb] = *(const bf16x8*)(lB + (wn * 64 + nb * 16 + l15) * 64 + cs);
        }
        __builtin_amdgcn_s_setprio(1);
        if (!vmode) {
#pragma unroll
            for (int kk = 0; kk < 2; kk++)
#pragma unroll
                for (int mb = 0; mb < 4; mb++)
#pragma unroll
                    for (int nb = 0; nb < 4; nb++)
                        acc[mb][nb] = mfma16(af[kk][mb], bfr[kk][nb], acc[mb][nb]);
        } else {
#pragma unroll
            for (int kk = 0; kk < 2; kk++)
#pragma unroll
                for (int mb = 0; mb < 4; mb++)
#pragma unroll
                    for (int nb = 0; nb < 4; nb++)
                        acc[mb][nb] = mfma16(bfr[kk][nb], af[kk][mb], acc[mb][nb]);  // D = C^T
        }
        __builtin_amdgcn_s_setprio(0);
    };

    // prologue: stage t0, t1; wait t0 (6 oldest of 12), publish
    STAGE(0, 0);
    STAGE(1, 1);
    WAITV6;
    BAR();

    int buf = 0;
    for (int t = 0; t < NTK - 2; t++) {
        int b2 = buf + 2; if (b2 >= 3) b2 -= 3;
        STAGE(b2, t + 2);
        COMPUTE(buf);
        WAITV6;                 // t+1 done, t+2 in flight
        BAR();
        buf++; if (buf == 3) buf = 0;
    }
    // tail: t = NTK-2, NTK-1
    COMPUTE(buf);
    WAITV0;
    BAR();
    buf++; if (buf == 3) buf = 0;
    COMPUTE(buf);

    // epilogue
    if (!vmode) {
#pragma unroll
        for (int nb = 0; nb < 4; nb++) {
            int n = n0 + wn * 64 + nb * 16 + l15;
            float bv = bias[n];
            int mat = n >> 11;        // 0=q, 1=k
            int h   = (n >> 7) & 15;
            int d   = n & 127;
            ushort_t* dst = (mat == 0) ? qws : kws;
#pragma unroll
            for (int mb = 0; mb < 4; mb++) {
#pragma unroll
                for (int r = 0; r < 4; r++) {
                    int m = m0 + wm * 64 + mb * 16 + quad * 4 + r;
                    int b = m >> 11;
                    int s = m & 2047;
                    dst[(((size_t)(b * 16 + h) * SS) + s) * DHEAD + d] =
                        f2bf(acc[mb][nb][r] + bv);
                }
            }
        }
    } else {
        const int b = m0 >> 11;
#pragma unroll
        for (int nb = 0; nb < 4; nb++) {
#pragma unroll
            for (int r = 0; r < 4; r++) {
                int n = n0 + wn * 64 + nb * 16 + quad * 4 + r;
                float bv = bias[n];
                int h = (n >> 7) & 15;
                int d = n & 127;
#pragma unroll
                for (int mb = 0; mb < 4; mb++) {
                    int s = (m0 & 2047) + wm * 64 + mb * 16 + l15;
                    vtws[(((size_t)(b * 16 + h) * DHEAD) + d) * SS + s] =
                        f2bf(acc[mb][nb][r] + bv);
                }
            }
        }
    }
}

// ---------------------------------------------------------------------------
// Dense GEMM — round-1 pipelined core (unchanged).
// ---------------------------------------------------------------------------
__global__ __launch_bounds__(512, 1) void dense_gemm_fast(
    const ushort_t* __restrict__ A,
    const ushort_t* __restrict__ W,
    const float* __restrict__ bias,
    float* __restrict__ out)
{
    __shared__ __align__(16) ushort_t smem[3 * BUFSZ];   // 144 KiB

    const int tid  = threadIdx.x;
    const int lane = tid & 63;
    const int w    = tid >> 6;
    const int wm   = w >> 1;
    const int wn   = w & 1;
    const int quad = lane >> 4;
    const int l15  = lane & 15;
    const int sub  = (lane & 7) ^ (lane >> 3);
    const int rloc = lane >> 3;
    const int m0 = blockIdx.y * BM;
    const int n0 = blockIdx.x * BN;

    const ushort_t* gA = A + (size_t)m0 * HID;
    const ushort_t* gB = W + (size_t)n0 * HID;

    f32x4 acc[4][4];
#pragma unroll
    for (int i = 0; i < 4; i++)
#pragma unroll
        for (int j = 0; j < 4; j++)
#pragma unroll
            for (int e = 0; e < 4; e++) acc[i][j][e] = 0.f;

    auto STAGE = [&](int bufi, int t) {
        ushort_t* lA = smem + bufi * BUFSZ;
        ushort_t* lB = lA + ASZ;
        const ushort_t* ga = gA + t * BKK;
        const ushort_t* gb = gB + t * BKK;
#pragma unroll
        for (int i = 0; i < 4; i++) {
            int blk = w * 4 + i;
            gload16(ga + (size_t)(blk * 8 + rloc) * HID + sub * 8, lA + blk * 512);
        }
#pragma unroll
        for (int i = 0; i < 2; i++) {
            int blk = w * 2 + i;
            gload16(gb + (size_t)(blk * 8 + rloc) * HID + sub * 8, lB + blk * 512);
        }
    };

    auto COMPUTE = [&](int bufi) {
        const ushort_t* lA = smem + bufi * BUFSZ;
        const ushort_t* lB = lA + ASZ;
        bf16x8 af[2][4], bfr[2][4];
#pragma unroll
        for (int kk = 0; kk < 2; kk++) {
            const int cs = ((kk * 4 + quad) ^ (l15 & 7)) << 3;
#pragma unroll
            for (int mb = 0; mb < 4; mb++)
                af[kk][mb] = *(const bf16x8*)(lA + (wm * 64 + mb * 16 + l15) * 64 + cs);
#pragma unroll
            for (int nb = 0; nb < 4; nb++)
                bfr[kk][nb] = *(const bf16x8*)(lB + (wn * 64 + nb * 16 + l15) * 64 + cs);
        }
        __builtin_amdgcn_s_setprio(1);
#pragma unroll
        for (int kk = 0; kk < 2; kk++)
#pragma unroll
            for (int mb = 0; mb < 4; mb++)
#pragma unroll
                for (int nb = 0; nb < 4; nb++)
                    acc[mb][nb] = mfma16(af[kk][mb], bfr[kk][nb], acc[mb][nb]);
        __builtin_amdgcn_s_setprio(0);
    };

    STAGE(0, 0);
    STAGE(1, 1);
    WAITV6;
    BAR();

    int buf = 0;
    for (int t = 0; t < NTK - 2; t++) {
        int b2 = buf + 2; if (b2 >= 3) b2 -= 3;
        STAGE(b2, t + 2);
        COMPUTE(buf);
        WAITV6;
        BAR();
        buf++; if (buf == 3) buf = 0;
    }
    COMPUTE(buf);
    WAITV0;
    BAR();
    buf++; if (buf == 3) buf = 0;
    COMPUTE(buf);

#pragma unroll
    for (int nb = 0; nb < 4; nb++) {
        int n = n0 + wn * 64 + nb * 16 + l15;
        float bv = bias[n];
#pragma unroll
        for (int mb = 0; mb < 4; mb++) {
#pragma unroll
            for (int r = 0; r < 4; r++) {
                int m = m0 + wm * 64 + mb * 16 + quad * 4 + r;
                out[(size_t)m * HID + n] = acc[mb][nb][r] + bv;
            }
        }
    }
}

// ---------------------------------------------------------------------------
// RoPE: vectorized (uint4 = 8 bf16 per access).  thread = (bh-group, s, d2g);
// each thread rotates 8 (d2, d2+64) pairs for 4 heads.
// ---------------------------------------------------------------------------
__global__ void rope_kernel3(ushort_t* __restrict__ qws, ushort_t* __restrict__ kws)
{
    int t = blockIdx.x * blockDim.x + threadIdx.x;   // 131072 threads
    int d2g = t & 7;
    int s   = (t >> 3) & 2047;
    int bh0 = (t >> 14) * 4;                          // 0..28 step 4

    float sn[8], cs[8];
#pragma unroll
    for (int jj = 0; jj < 8; jj++) {
        int d2 = d2g * 8 + jj;
        float inv_freq = exp2f(-(float)d2 * (13.287712379549449f / 64.f));
        float fr = (float)s * inv_freq;
        sincosf(fr, &sn[jj], &cs[jj]);
    }

    size_t base0 = (size_t)s * DHEAD + d2g * 8;
#pragma unroll
    for (int q = 0; q < 4; q++) {
        size_t base = base0 + (size_t)(bh0 + q) * (SS * DHEAD);
        {
            union { ushort_t u[8]; uint4 v; } x1, x2, y1, y2;
            x1.v = *(const uint4*)(qws + base);
            x2.v = *(const uint4*)(qws + base + 64);
#pragma unroll
            for (int jj = 0; jj < 8; jj++) {
                float a = bf2f(x1.u[jj]), b = bf2f(x2.u[jj]);
                y1.u[jj] = f2bf(a * cs[jj] - b * sn[jj]);
                y2.u[jj] = f2bf(b * cs[jj] + a * sn[jj]);
            }
            *(uint4*)(qws + base) = y1.v;
            *(uint4*)(qws + base + 64) = y2.v;
        }
        {
            union { ushort_t u[8]; uint4 v; } x1, x2, y1, y2;
            x1.v = *(const uint4*)(kws + base);
            x2.v = *(const uint4*)(kws + base + 64);
#pragma unroll
            for (int jj = 0; jj < 8; jj++) {
                float a = bf2f(x1.u[jj]), b = bf2f(x2.u[jj]);
                y1.u[jj] = f2bf(a * cs[jj] - b * sn[jj]);
                y2.u[jj] = f2bf(b * cs[jj] + a * sn[jj]);
            }
            *(uint4*)(kws + base) = y1.v;
            *(uint4*)(kws + base + 64) = y2.v;
        }
    }
}

// ---------------------------------------------------------------------------
// Causal flash attention v6: 128-row paired q-tiles (qA=tA*128, qB=(15-tA)*128),
// 512 threads = 8 waves (wave w owns rows +w*16 of both tiles — per-wave inner
// code identical to the verified 4-wave version).  K AND V double-buffered,
// counted vmcnt (4/2/0 with 2-load staging granularity), 3 barriers/iter.
// 256 blocks = 1/CU, 100 KiB LDS.  Per staged K/V tile, 256 q-rows are
// processed (2x the old 128) -> per-iter overhead amortized 2x, K/V HBM
// traffic per head halved.
// ---------------------------------------------------------------------------
#define LDP 72

__global__ __launch_bounds__(512, 1) void attn_kernel6(
    const ushort_t* __restrict__ qws,
    const ushort_t* __restrict__ kws,
    const ushort_t* __restrict__ vtws,
    ushort_t* __restrict__ aout)
{
    __shared__ __align__(16) ushort_t k_s[2][64 * 128];   // 2 x 16 KiB, swizzled
    __shared__ __align__(16) ushort_t vt_s[2][128 * 64];  // 2 x 16 KiB, swizzled
    __shared__ __align__(16) ushort_t pA_s[8][16 * LDP];  // 18 KiB
    __shared__ __align__(16) ushort_t pB_s[8][16 * LDP];  // 18 KiB

    const int tid  = threadIdx.x;
    const int lane = tid & 63;
    const int w    = tid >> 6;            // 0..7
    const int quad = lane >> 4;
    const int l15  = lane & 15;

    const int g  = blockIdx.x;                       // 0..255
    const int bh = (g & 7) | (((g >> 3) & 3) << 3);  // head pinned to XCD g%8
    const int tA = g >> 5;                           // 0..7
    const int tB = 15 - tA;                          // 15..8
    const int qA = tA * 128, qB = tB * 128;
    const int jAmax = 2 * tA + 1;
    const int jBmax = 2 * tB + 1;
    const size_t qk_base = (size_t)bh * SS * DHEAD;

    // Q fragments in registers (wave w: rows qA+w*16.., qB+w*16..)
    bf16x8 qa[4], qb[4];
    {
        const ushort_t* rowA = qws + qk_base + (size_t)(qA + w * 16 + l15) * DHEAD;
        const ushort_t* rowB = qws + qk_base + (size_t)(qB + w * 16 + l15) * DHEAD;
#pragma unroll
        for (int kc = 0; kc < 4; kc++) {
            qa[kc] = *(const bf16x8*)(rowA + kc * 32 + quad * 8);
            qb[kc] = *(const bf16x8*)(rowB + kc * 32 + quad * 8);
        }
    }

    // ones B-fragment (bf16 1.0 = 0x3F80)
    bf16x8 ones;
#pragma unroll
    for (int i = 0; i < 8; i++) ones[i] = (short)0x3F80;

    f32x4 oA[8], oB[8], lA, lB;
#pragma unroll
    for (int i = 0; i < 8; i++)
#pragma unroll
        for (int e = 0; e < 4; e++) { oA[i][e] = 0.f; oB[i][e] = 0.f; }
#pragma unroll
    for (int e = 0; e < 4; e++) { lA[e] = 0.f; lB[e] = 0.f; }

    const int srowK = lane >> 4;
    const int srowV = lane >> 3;
    const int ccgV  = (lane & 7) ^ (lane >> 3);

    const int q_baseA = qA + w * 16 + quad * 4;
    const int q_baseB = qB + w * 16 + quad * 4;
    const int xorv = l15 & 7;

    const float scale2 = 0.12753102015727466f;  // (1/sqrt(128)) * log2(e)
    const float FM = 16.0f;                     // fixed softmax max (exp2 domain)

    // staging: 512 lanes x 16B = 8 KiB per call-iter -> 2 iters per 16 KiB tile
    auto KSTAGE = [&](int j, int slot) {
        const int kb = j * 64;
#pragma unroll
        for (int i = 0; i < 2; i++) {
            int P = i * 8 + w;                   // 0..15
            int row = P * 4 + srowK;
            int ccg = l15 ^ (((P & 1) * 4) + srowK);
            gload16(kws + qk_base + (size_t)(kb + row) * DHEAD + ccg * 8,
                    k_s[slot] + P * 512);
        }
    };
    auto VSTAGE = [&](int j, int slot) {
        const int kb = j * 64;
#pragma unroll
        for (int i = 0; i < 2; i++) {
            int P = i * 8 + w;                   // 0..15
            int row = P * 8 + srowV;
            gload16(vtws + qk_base + (size_t)row * SS + kb + ccgV * 8,
                    vt_s[slot] + P * 512);
        }
    };

    // prologue: K(0) in flight (2 loads/wave)
    KSTAGE(0, 0);

    for (int j = 0; j <= jBmax; j++) {
        const int kb = j * 64;
        const int slot = j & 1;

        VSTAGE(j, slot);                   // +2 (older than K(j+1))
        if (j < jBmax) {
            KSTAGE(j + 1, slot ^ 1);       // +2
            WAITV4;                        // K(j) landed; V(j)+K(j+1) in flight
        } else {
            WAITV2;                        // K(j) landed; V(j) in flight
        }
        BAR();                             // publish K(j)

        f32x4 sA[4], sB[4];
#pragma unroll
        for (int nb = 0; nb < 4; nb++)
#pragma unroll
            for (int e = 0; e < 4; e++) { sA[nb][e] = 0.f; sB[nb][e] = 0.f; }

        const ushort_t* ks = k_s[slot];
        const ushort_t* vs = vt_s[slot];

        if (j <= jAmax) {
#pragma unroll
            for (int kc = 0; kc < 4; kc++) {
#pragma unroll
                for (int nb = 0; nb < 4; nb++) {
                    int cc_s = (kc * 4 + quad) ^ xorv;
                    bf16x8 kf = *(const bf16x8*)(ks + (nb * 16 + l15) * 128 + cc_s * 8);
                    sA[nb] = mfma16(qa[kc], kf, sA[nb]);
                    sB[nb] = mfma16(qb[kc], kf, sB[nb]);
                }
            }
#pragma unroll
            for (int nb = 0; nb < 4; nb++) {
                int kidx = kb + nb * 16 + l15;
#pragma unroll
                for (int r = 0; r < 4; r++) {
                    float pa = exp2f(sA[nb][r] * scale2 - FM);
                    float pb = exp2f(sB[nb][r] * scale2 - FM);
                    pa = (kidx <= q_baseA + r) ? pa : 0.f;
                    pb = (kidx <= q_baseB + r) ? pb : 0.f;
                    pA_s[w][(quad * 4 + r) * LDP + nb * 16 + l15] = f2bf(pa);
                    pB_s[w][(quad * 4 + r) * LDP + nb * 16 + l15] = f2bf(pb);
                }
            }
            if (j < jBmax) { WAITV2; } else { WAITV0; }   // V(j) landed
            BAR();                                         // publish V(j)
#pragma unroll
            for (int kc = 0; kc < 2; kc++) {
                bf16x8 pa = *(const bf16x8*)(pA_s[w] + l15 * LDP + kc * 32 + quad * 8);
                bf16x8 pb = *(const bf16x8*)(pB_s[w] + l15 * LDP + kc * 32 + quad * 8);
                lA = mfma16(pa, ones, lA);
                lB = mfma16(pb, ones, lB);
#pragma unroll
                for (int db = 0; db < 8; db++) {
                    int cc_s = (kc * 4 + quad) ^ xorv;
                    bf16x8 vf = *(const bf16x8*)(vs + (db * 16 + l15) * 64 + cc_s * 8);
                    oA[db] = mfma16(pa, vf, oA[db]);
                    oB[db] = mfma16(pb, vf, oB[db]);
                }
            }
        } else {
#pragma unroll
            for (int kc = 0; kc < 4; kc++) {
#pragma unroll
                for (int nb = 0; nb < 4; nb++) {
                    int cc_s = (kc * 4 + quad) ^ xorv;
                    bf16x8 kf = *(const bf16x8*)(ks + (nb * 16 + l15) * 128 + cc_s * 8);
                    sB[nb] = mfma16(qb[kc], kf, sB[nb]);
                }
            }
#pragma unroll
            for (int nb = 0; nb < 4; nb++) {
                int kidx = kb + nb * 16 + l15;
#pragma unroll
                for (int r = 0; r < 4; r++) {
                    float pb = exp2f(sB[nb][r] * scale2 - FM);
                    pb = (kidx <= q_baseB + r) ? pb : 0.f;
                    pB_s[w][(quad * 4 + r) * LDP + nb * 16 + l15] = f2bf(pb);
                }
            }
            if (j < jBmax) { WAITV2; } else { WAITV0; }   // V(j) landed
            BAR();                                         // publish V(j)
#pragma unroll
            for (int kc = 0; kc < 2; kc++) {
                bf16x8 pb = *(const bf16x8*)(pB_s[w] + l15 * LDP + kc * 32 + quad * 8);
                lB = mfma16(pb, ones, lB);
#pragma unroll
                for (int db = 0; db < 8; db++) {
                    int cc_s = (kc * 4 + quad) ^ xorv;
                    bf16x8 vf = *(const bf16x8*)(vs + (db * 16 + l15) * 64 + cc_s * 8);
                    oB[db] = mfma16(pb, vf, oB[db]);
                }
            }
        }
        BAR();   // K/V slot consumed -> safe to overwrite 2 iters later
    }

    // epilogue: aout[b*S + s][h*128 + d] (bf16)
    const int b = bh >> 4;
    const int h = bh & 15;
    float invA[4], invB[4];
#pragma unroll
    for (int r = 0; r < 4; r++) { invA[r] = 1.f / lA[r]; invB[r] = 1.f / lB[r]; }
#pragma unroll
    for (int db = 0; db < 8; db++) {
#pragma unroll
        for (int r = 0; r < 4; r++) {
            int sA_row = qA + w * 16 + quad * 4 + r;
            int sB_row = qB + w * 16 + quad * 4 + r;
            size_t offA = ((size_t)(b * SS + sA_row)) * HID + h * DHEAD + db * 16 + l15;
            size_t offB = ((size_t)(b * SS + sB_row)) * HID + h * DHEAD + db * 16 + l15;
            aout[offA] = f2bf(oA[db][r] * invA[r]);
            aout[offB] = f2bf(oB[db][r] * invB[r]);
        }
    }
}

// ---------------------------------------------------------------------------
extern "C" void kernel_launch(void* const* d_in, const int* in_sizes, int n_in,
                              void* d_out, int out_size, void* d_ws, size_t ws_size,
                              hipStream_t stream)
{
    const float* X    = (const float*)d_in[0];
    const float* Wqkv = (const float*)d_in[1];
    const float* bqkv = (const float*)d_in[2];
    const float* Wd   = (const float*)d_in[3];
    const float* bd   = (const float*)d_in[4];
    float* out = (float*)d_out;

    char* ws = (char*)d_ws;
    const size_t MB = 1048576;
    ushort_t* qws  = (ushort_t*)(ws);              // 16 MiB [B,H,S,D] bf16
    ushort_t* kws  = (ushort_t*)(ws + 16 * MB);    // 16 MiB
    ushort_t* vtws = (ushort_t*)(ws + 32 * MB);    // 16 MiB [B,H,D,S]
    ushort_t* aout = (ushort_t*)(ws + 48 * MB);    // 16 MiB [B*S,HID] (aliases Xbf)
    ushort_t* Xbf  = (ushort_t*)(ws + 48 * MB);    // dead after qkv; aout reuses
    ushort_t* Wqbf = (ushort_t*)(ws + 64 * MB);    // 24 MiB
    ushort_t* Wdbf = (ushort_t*)(ws + 88 * MB);    // 8 MiB

    const int nX = MM * HID / 8, nWq = NQKV * HID / 8, nWd = HID * HID / 8;
    cvt3_kernel<<<(nX + nWq + nWd + 255) / 256, 256, 0, stream>>>(
        X, Xbf, nX, Wqkv, Wqbf, nWq, Wd, Wdbf, nWd);

    qkv_gemm_fast<<<dim3(NQKV / BN, MM / BM), 512, 0, stream>>>(Xbf, Wqbf, bqkv, qws, kws, vtws);
    rope_kernel3<<<(SS * 8 * 8) / 256, 256, 0, stream>>>(qws, kws);
    attn_kernel6<<<dim3(256), 512, 0, stream>>>(qws, kws, vtws, aout);
    dense_gemm_fast<<<dim3(HID / BN, MM / BM), 512, 0, stream>>>(aout, Wdbf, bd, out);
}

// Round 6
// 372.102 us; speedup vs baseline: 1.0385x; 1.0385x over previous
//
#include <hip/hip_runtime.h>
#include <hip/hip_bf16.h>
#include <stdint.h>

#define HID 2048
#define NHEAD 16
#define DHEAD 128
#define BB 2
#define SS 2048
#define MM (BB*SS)       // 4096
#define NQKV (3*HID)     // 6144
#define NT (SS/64)       // 32 k-tiles / q-tiles per head

typedef __attribute__((ext_vector_type(8))) short bf16x8;
typedef __attribute__((ext_vector_type(4))) float f32x4;
typedef unsigned short ushort_t;

__device__ __forceinline__ f32x4 mfma16(bf16x8 a, bf16x8 b, f32x4 c) {
    return __builtin_amdgcn_mfma_f32_16x16x32_bf16(a, b, c, 0, 0, 0);
}

__device__ __forceinline__ float bf2f(ushort_t u) {
    unsigned int x = ((unsigned int)u) << 16;
    return __builtin_bit_cast(float, x);
}
__device__ __forceinline__ ushort_t f2bf(float f) {
    unsigned int x = __builtin_bit_cast(unsigned int, f);
    unsigned int r = (x + 0x7FFFu + ((x >> 16) & 1u)) >> 16;
    return (ushort_t)r;
}

// packed f32x2 -> bf16x2 (RNE), one instruction; no builtin on gfx950 (m240)
__device__ __forceinline__ unsigned int cvtpk(float lo, float hi) {
    unsigned int r;
    asm volatile("v_cvt_pk_bf16_f32 %0, %1, %2" : "=v"(r) : "v"(lo), "v"(hi));
    return r;
}

__device__ __forceinline__ void cvt8(const float* __restrict__ g, ushort_t* l) {
    float4 a = *(const float4*)g;
    float4 b = *(const float4*)(g + 4);
    union { ushort_t u[8]; uint4 v; } t;
    t.u[0] = f2bf(a.x); t.u[1] = f2bf(a.y); t.u[2] = f2bf(a.z); t.u[3] = f2bf(a.w);
    t.u[4] = f2bf(b.x); t.u[5] = f2bf(b.y); t.u[6] = f2bf(b.z); t.u[7] = f2bf(b.w);
    *(uint4*)l = t.v;
}

// async global->LDS, 16 bytes per lane; LDS base wave-uniform, HW adds lane*16
__device__ __forceinline__ void gload16(const ushort_t* g, ushort_t* l) {
    __builtin_amdgcn_global_load_lds(
        (const __attribute__((address_space(1))) unsigned int*)(const void*)g,
        (__attribute__((address_space(3))) unsigned int*)(void*)l,
        16, 0, 0);
}

#define WAITV0 asm volatile("s_waitcnt vmcnt(0)" ::: "memory")
#define WAITV4 asm volatile("s_waitcnt vmcnt(4)" ::: "memory")
#define WAITV6 asm volatile("s_waitcnt vmcnt(6)" ::: "memory")
#define WAITV8 asm volatile("s_waitcnt vmcnt(8)" ::: "memory")
#define BAR()  __builtin_amdgcn_s_barrier()

// ---------------------------------------------------------------------------
// f32 -> bf16 bulk convert, all three tensors in one launch
// ---------------------------------------------------------------------------
__global__ void cvt3_kernel(const float* __restrict__ a, ushort_t* __restrict__ da, int na,
                            const float* __restrict__ b, ushort_t* __restrict__ db, int nb,
                            const float* __restrict__ c, ushort_t* __restrict__ dc, int nc)
{
    int i = blockIdx.x * blockDim.x + threadIdx.x;
    if (i < na) {
        cvt8(a + (size_t)i * 8, da + (size_t)i * 8);
    } else if (i < na + nb) {
        int j = i - na;
        cvt8(b + (size_t)j * 8, db + (size_t)j * 8);
    } else if (i < na + nb + nc) {
        int j = i - na - nb;
        cvt8(c + (size_t)j * 8, dc + (size_t)j * 8);
    }
}

// ---------------------------------------------------------------------------
// QKV GEMM (round-1 proven core): BM=256, BN=128, BK=64, 512 thr = 8 waves,
// 3 rotating LDS buffers, counted vmcnt(6), T2 swizzle, T5 setprio.
// For V blocks (n0 >= 4096) MFMA operands SWAPPED so acc holds C^T.
// ---------------------------------------------------------------------------
#define BM 256
#define BN 128
#define BKK 64
#define NTK (HID/BKK)         // 32
#define ASZ (BM*BKK)          // 16384 ushorts (32 KiB)
#define BSZ (BN*BKK)          // 8192 ushorts (16 KiB)
#define BUFSZ (ASZ+BSZ)       // 24576 ushorts (48 KiB)

__global__ __launch_bounds__(512, 1) void qkv_gemm_fast(
    const ushort_t* __restrict__ X,
    const ushort_t* __restrict__ W,
    const float* __restrict__ bias,
    ushort_t* __restrict__ qws,
    ushort_t* __restrict__ kws,
    ushort_t* __restrict__ vtws)
{
    __shared__ __align__(16) ushort_t smem[3 * BUFSZ];   // 144 KiB

    const int tid  = threadIdx.x;
    const int lane = tid & 63;
    const int w    = tid >> 6;            // 0..7
    const int wm   = w >> 1, wn = w & 1;
    const int quad = lane >> 4;
    const int l15  = lane & 15;
    const int sub  = (lane & 7) ^ (lane >> 3);   // inverse-swizzled src chunk
    const int rloc = lane >> 3;                  // row within 8-row block
    const int m0 = blockIdx.y * BM;
    const int n0 = blockIdx.x * BN;
    const bool vmode = (n0 >= 2 * HID);

    const ushort_t* gA = X + (size_t)m0 * HID;
    const ushort_t* gB = W + (size_t)n0 * HID;

    f32x4 acc[4][4];
#pragma unroll
    for (int i = 0; i < 4; i++)
#pragma unroll
        for (int j = 0; j < 4; j++)
#pragma unroll
            for (int e = 0; e < 4; e++) acc[i][j][e] = 0.f;

    auto STAGE = [&](int bufi, int t) {
        ushort_t* lA = smem + bufi * BUFSZ;
        ushort_t* lB = lA + ASZ;
        const ushort_t* ga = gA + t * BKK;
        const ushort_t* gb = gB + t * BKK;
#pragma unroll
        for (int i = 0; i < 4; i++) {
            int blk = w * 4 + i;                 // 0..31 -> A rows blk*8..+7
            gload16(ga + (size_t)(blk * 8 + rloc) * HID + sub * 8, lA + blk * 512);
        }
#pragma unroll
        for (int i = 0; i < 2; i++) {
            int blk = w * 2 + i;                 // 0..15 -> B rows blk*8..+7
            gload16(gb + (size_t)(blk * 8 + rloc) * HID + sub * 8, lB + blk * 512);
        }
    };

    auto COMPUTE = [&](int bufi) {
        const ushort_t* lA = smem + bufi * BUFSZ;
        const ushort_t* lB = lA + ASZ;
        bf16x8 af[2][4], bfr[2][4];
#pragma unroll
        for (int kk = 0; kk < 2; kk++) {
            const int cs = ((kk * 4 + quad) ^ (l15 & 7)) << 3;   // swizzled chunk
#pragma unroll
            for (int mb = 0; mb < 4; mb++)
                af[kk][mb] = *(const bf16x8*)(lA + (wm * 64 + mb * 16 + l15) * 64 + cs);
#pragma unroll
            for (int nb = 0; nb < 4; nb++)
                bfr[kk][nb] = *(const bf16x8*)(lB + (wn * 64 + nb * 16 + l15) * 64 + cs);
        }
        __builtin_amdgcn_s_setprio(1);
        if (!vmode) {
#pragma unroll
            for (int kk = 0; kk < 2; kk++)
#pragma unroll
                for (int mb = 0; mb < 4; mb++)
#pragma unroll
                    for (int nb = 0; nb < 4; nb++)
                        acc[mb][nb] = mfma16(af[kk][mb], bfr[kk][nb], acc[mb][nb]);
        } else {
#pragma unroll
            for (int kk = 0; kk < 2; kk++)
#pragma unroll
                for (int mb = 0; mb < 4; mb++)
#pragma unroll
                    for (int nb = 0; nb < 4; nb++)
                        acc[mb][nb] = mfma16(bfr[kk][nb], af[kk][mb], acc[mb][nb]);  // D = C^T
        }
        __builtin_amdgcn_s_setprio(0);
    };

    // prologue: stage t0, t1; wait t0 (6 oldest of 12), publish
    STAGE(0, 0);
    STAGE(1, 1);
    WAITV6;
    BAR();

    int buf = 0;
    for (int t = 0; t < NTK - 2; t++) {
        int b2 = buf + 2; if (b2 >= 3) b2 -= 3;
        STAGE(b2, t + 2);
        COMPUTE(buf);
        WAITV6;                 // t+1 done, t+2 in flight
        BAR();
        buf++; if (buf == 3) buf = 0;
    }
    // tail: t = NTK-2, NTK-1
    COMPUTE(buf);
    WAITV0;
    BAR();
    buf++; if (buf == 3) buf = 0;
    COMPUTE(buf);

    // epilogue
    if (!vmode) {
#pragma unroll
        for (int nb = 0; nb < 4; nb++) {
            int n = n0 + wn * 64 + nb * 16 + l15;
            float bv = bias[n];
            int mat = n >> 11;        // 0=q, 1=k
            int h   = (n >> 7) & 15;
            int d   = n & 127;
            ushort_t* dst = (mat == 0) ? qws : kws;
#pragma unroll
            for (int mb = 0; mb < 4; mb++) {
#pragma unroll
                for (int r = 0; r < 4; r++) {
                    int m = m0 + wm * 64 + mb * 16 + quad * 4 + r;
                    int b = m >> 11;
                    int s = m & 2047;
                    dst[(((size_t)(b * 16 + h) * SS) + s) * DHEAD + d] =
                        f2bf(acc[mb][nb][r] + bv);
                }
            }
        }
    } else {
        const int b = m0 >> 11;
#pragma unroll
        for (int nb = 0; nb < 4; nb++) {
#pragma unroll
            for (int r = 0; r < 4; r++) {
                int n = n0 + wn * 64 + nb * 16 + quad * 4 + r;
                float bv = bias[n];
                int h = (n >> 7) & 15;
                int d = n & 127;
#pragma unroll
                for (int mb = 0; mb < 4; mb++) {
                    int s = (m0 & 2047) + wm * 64 + mb * 16 + l15;
                    vtws[(((size_t)(b * 16 + h) * DHEAD) + d) * SS + s] =
                        f2bf(acc[mb][nb][r] + bv);
                }
            }
        }
    }
}

// ---------------------------------------------------------------------------
// Dense GEMM — round-1 pipelined core (unchanged).
// ---------------------------------------------------------------------------
__global__ __launch_bounds__(512, 1) void dense_gemm_fast(
    const ushort_t* __restrict__ A,
    const ushort_t* __restrict__ W,
    const float* __restrict__ bias,
    float* __restrict__ out)
{
    __shared__ __align__(16) ushort_t smem[3 * BUFSZ];   // 144 KiB

    const int tid  = threadIdx.x;
    const int lane = tid & 63;
    const int w    = tid >> 6;
    const int wm   = w >> 1;
    const int wn   = w & 1;
    const int quad = lane >> 4;
    const int l15  = lane & 15;
    const int sub  = (lane & 7) ^ (lane >> 3);
    const int rloc = lane >> 3;
    const int m0 = blockIdx.y * BM;
    const int n0 = blockIdx.x * BN;

    const ushort_t* gA = A + (size_t)m0 * HID;
    const ushort_t* gB = W + (size_t)n0 * HID;

    f32x4 acc[4][4];
#pragma unroll
    for (int i = 0; i < 4; i++)
#pragma unroll
        for (int j = 0; j < 4; j++)
#pragma unroll
            for (int e = 0; e < 4; e++) acc[i][j][e] = 0.f;

    auto STAGE = [&](int bufi, int t) {
        ushort_t* lA = smem + bufi * BUFSZ;
        ushort_t* lB = lA + ASZ;
        const ushort_t* ga = gA + t * BKK;
        const ushort_t* gb = gB + t * BKK;
#pragma unroll
        for (int i = 0; i < 4; i++) {
            int blk = w * 4 + i;
            gload16(ga + (size_t)(blk * 8 + rloc) * HID + sub * 8, lA + blk * 512);
        }
#pragma unroll
        for (int i = 0; i < 2; i++) {
            int blk = w * 2 + i;
            gload16(gb + (size_t)(blk * 8 + rloc) * HID + sub * 8, lB + blk * 512);
        }
    };

    auto COMPUTE = [&](int bufi) {
        const ushort_t* lA = smem + bufi * BUFSZ;
        const ushort_t* lB = lA + ASZ;
        bf16x8 af[2][4], bfr[2][4];
#pragma unroll
        for (int kk = 0; kk < 2; kk++) {
            const int cs = ((kk * 4 + quad) ^ (l15 & 7)) << 3;
#pragma unroll
            for (int mb = 0; mb < 4; mb++)
                af[kk][mb] = *(const bf16x8*)(lA + (wm * 64 + mb * 16 + l15) * 64 + cs);
#pragma unroll
            for (int nb = 0; nb < 4; nb++)
                bfr[kk][nb] = *(const bf16x8*)(lB + (wn * 64 + nb * 16 + l15) * 64 + cs);
        }
        __builtin_amdgcn_s_setprio(1);
#pragma unroll
        for (int kk = 0; kk < 2; kk++)
#pragma unroll
            for (int mb = 0; mb < 4; mb++)
#pragma unroll
                for (int nb = 0; nb < 4; nb++)
                    acc[mb][nb] = mfma16(af[kk][mb], bfr[kk][nb], acc[mb][nb]);
        __builtin_amdgcn_s_setprio(0);
    };

    STAGE(0, 0);
    STAGE(1, 1);
    WAITV6;
    BAR();

    int buf = 0;
    for (int t = 0; t < NTK - 2; t++) {
        int b2 = buf + 2; if (b2 >= 3) b2 -= 3;
        STAGE(b2, t + 2);
        COMPUTE(buf);
        WAITV6;
        BAR();
        buf++; if (buf == 3) buf = 0;
    }
    COMPUTE(buf);
    WAITV0;
    BAR();
    buf++; if (buf == 3) buf = 0;
    COMPUTE(buf);

#pragma unroll
    for (int nb = 0; nb < 4; nb++) {
        int n = n0 + wn * 64 + nb * 16 + l15;
        float bv = bias[n];
#pragma unroll
        for (int mb = 0; mb < 4; mb++) {
#pragma unroll
            for (int r = 0; r < 4; r++) {
                int m = m0 + wm * 64 + mb * 16 + quad * 4 + r;
                out[(size_t)m * HID + n] = acc[mb][nb][r] + bv;
            }
        }
    }
}

// ---------------------------------------------------------------------------
// RoPE: vectorized (uint4 = 8 bf16 per access).  thread = (bh-group, s, d2g);
// each thread rotates 8 (d2, d2+64) pairs for 4 heads.
// ---------------------------------------------------------------------------
__global__ void rope_kernel3(ushort_t* __restrict__ qws, ushort_t* __restrict__ kws)
{
    int t = blockIdx.x * blockDim.x + threadIdx.x;   // 131072 threads
    int d2g = t & 7;
    int s   = (t >> 3) & 2047;
    int bh0 = (t >> 14) * 4;                          // 0..28 step 4

    float sn[8], cs[8];
#pragma unroll
    for (int jj = 0; jj < 8; jj++) {
        int d2 = d2g * 8 + jj;
        float inv_freq = exp2f(-(float)d2 * (13.287712379549449f / 64.f));
        float fr = (float)s * inv_freq;
        sincosf(fr, &sn[jj], &cs[jj]);
    }

    size_t base0 = (size_t)s * DHEAD + d2g * 8;
#pragma unroll
    for (int q = 0; q < 4; q++) {
        size_t base = base0 + (size_t)(bh0 + q) * (SS * DHEAD);
        {
            union { ushort_t u[8]; uint4 v; } x1, x2, y1, y2;
            x1.v = *(const uint4*)(qws + base);
            x2.v = *(const uint4*)(qws + base + 64);
#pragma unroll
            for (int jj = 0; jj < 8; jj++) {
                float a = bf2f(x1.u[jj]), b = bf2f(x2.u[jj]);
                y1.u[jj] = f2bf(a * cs[jj] - b * sn[jj]);
                y2.u[jj] = f2bf(b * cs[jj] + a * sn[jj]);
            }
            *(uint4*)(qws + base) = y1.v;
            *(uint4*)(qws + base + 64) = y2.v;
        }
        {
            union { ushort_t u[8]; uint4 v; } x1, x2, y1, y2;
            x1.v = *(const uint4*)(kws + base);
            x2.v = *(const uint4*)(kws + base + 64);
#pragma unroll
            for (int jj = 0; jj < 8; jj++) {
                float a = bf2f(x1.u[jj]), b = bf2f(x2.u[jj]);
                y1.u[jj] = f2bf(a * cs[jj] - b * sn[jj]);
                y2.u[jj] = f2bf(b * cs[jj] + a * sn[jj]);
            }
            *(uint4*)(kws + base) = y1.v;
            *(uint4*)(kws + base + 64) = y2.v;
        }
    }
}

// ---------------------------------------------------------------------------
// Causal flash attention v7 = r3-verified attn5 skeleton (4 waves, dbuf-K,
// counted vmcnt 8/4/0, 3 barriers/iter, 2 blocks/CU) with SWAPPED QK^T:
//   sX[nb] = sum_kc mfma(kf, qX)  ->  S^T: lane&15 = q, k = nb*16+quad*4+r
//   (4 consecutive k per register quad).
// Softmax P-path: 2x v_cvt_pk_bf16_f32 + ONE ds_write_b64 per nb (8 packed
// writes + 16 cvt_pk / wave / iter) replacing 64 scalar u16 writes + ~256
// VALU ops of manual f2bf.  LDS P layout in memory is IDENTICAL to before
// (P[q][k] at q*LDP + k), so the PV read path, ones-MFMA row sums, masking
// semantics, and epilogue are unchanged.  K/V loads unchanged (A/B fragment
// layouts are symmetric).
// ---------------------------------------------------------------------------
#define LDP 72

__global__ __launch_bounds__(256, 2) void attn_kernel7(
    const ushort_t* __restrict__ qws,
    const ushort_t* __restrict__ kws,
    const ushort_t* __restrict__ vtws,
    ushort_t* __restrict__ aout)
{
    __shared__ __align__(16) ushort_t k_s[2][64 * 128];  // 2 x 16 KiB, swizzled
    __shared__ __align__(16) ushort_t vt_s[128 * 64];    // 16 KiB, swizzled
    __shared__ __align__(16) ushort_t pA_s[4][16 * LDP];
    __shared__ __align__(16) ushort_t pB_s[4][16 * LDP];

    const int tid  = threadIdx.x;
    const int lane = tid & 63;
    const int w    = tid >> 6;
    const int quad = lane >> 4;
    const int l15  = lane & 15;

    const int g  = blockIdx.x;                       // 0..511
    const int bh = (g & 7) | (((g >> 3) & 3) << 3);  // head pinned to XCD g%8
    const int tA = g >> 5;                           // 0..15
    const int tB = NT - 1 - tA;                      // 31..16
    const int qA = tA * 64, qB = tB * 64;
    const size_t qk_base = (size_t)bh * SS * DHEAD;

    // Q fragments in registers
    bf16x8 qa[4], qb[4];
    {
        const ushort_t* rowA = qws + qk_base + (size_t)(qA + w * 16 + l15) * DHEAD;
        const ushort_t* rowB = qws + qk_base + (size_t)(qB + w * 16 + l15) * DHEAD;
#pragma unroll
        for (int kc = 0; kc < 4; kc++) {
            qa[kc] = *(const bf16x8*)(rowA + kc * 32 + quad * 8);
            qb[kc] = *(const bf16x8*)(rowB + kc * 32 + quad * 8);
        }
    }

    // ones B-fragment (bf16 1.0 = 0x3F80)
    bf16x8 ones;
#pragma unroll
    for (int i = 0; i < 8; i++) ones[i] = (short)0x3F80;

    f32x4 oA[8], oB[8], lA, lB;
#pragma unroll
    for (int i = 0; i < 8; i++)
#pragma unroll
        for (int e = 0; e < 4; e++) { oA[i][e] = 0.f; oB[i][e] = 0.f; }
#pragma unroll
    for (int e = 0; e < 4; e++) { lA[e] = 0.f; lB[e] = 0.f; }

    const int srowK = lane >> 4;
    const int srowV = lane >> 3;
    const int ccgV  = (lane & 7) ^ (lane >> 3);

    // swapped layout: q = l15 per lane, k = kb + nb*16 + quad*4 + r
    const int qrA = qA + w * 16 + l15;
    const int qrB = qB + w * 16 + l15;
    const int xorv = l15 & 7;

    const float scale2 = 0.12753102015727466f;  // (1/sqrt(128)) * log2(e)
    const float FM = 16.0f;                     // fixed softmax max (exp2 domain)

    auto KSTAGE = [&](int j, int slot) {
        const int kb = j * 64;
#pragma unroll
        for (int i = 0; i < 4; i++) {
            int P = i * 4 + w;
            int row = P * 4 + srowK;
            int ccg = l15 ^ (((P & 1) * 4) + srowK);
            gload16(kws + qk_base + (size_t)(kb + row) * DHEAD + ccg * 8,
                    k_s[slot] + P * 512);
        }
    };
    auto VSTAGE = [&](int j) {
        const int kb = j * 64;
#pragma unroll
        for (int i = 0; i < 4; i++) {
            int P = i * 4 + w;
            int row = P * 8 + srowV;
            gload16(vtws + qk_base + (size_t)row * SS + kb + ccgV * 8,
                    vt_s + P * 512);
        }
    };

    // prologue: K(0) in flight (4 loads/wave)
    KSTAGE(0, 0);

    for (int j = 0; j <= tB; j++) {
        const int kb = j * 64;
        const int slot = j & 1;

        VSTAGE(j);                         // 4 loads (older)
        if (j < tB) {
            KSTAGE(j + 1, slot ^ 1);       // 4 loads (newer)
            WAITV8;                        // K(j) landed; V(j)+K(j+1) in flight
        } else {
            WAITV4;                        // K(j) landed; V(j) in flight
        }
        BAR();                             // publish K(j) to all waves

        f32x4 sA[4], sB[4];
#pragma unroll
        for (int nb = 0; nb < 4; nb++)
#pragma unroll
            for (int e = 0; e < 4; e++) { sA[nb][e] = 0.f; sB[nb][e] = 0.f; }

        const ushort_t* ks = k_s[slot];

        if (j <= tA) {
#pragma unroll
            for (int kc = 0; kc < 4; kc++) {
#pragma unroll
                for (int nb = 0; nb < 4; nb++) {
                    int cc_s = (kc * 4 + quad) ^ xorv;
                    bf16x8 kf = *(const bf16x8*)(ks + (nb * 16 + l15) * 128 + cc_s * 8);
                    sA[nb] = mfma16(kf, qa[kc], sA[nb]);   // swapped: S^T
                    sB[nb] = mfma16(kf, qb[kc], sB[nb]);
                }
            }
#pragma unroll
            for (int nb = 0; nb < 4; nb++) {
                int k0 = kb + nb * 16 + quad * 4;
                float pa[4], pb[4];
#pragma unroll
                for (int r = 0; r < 4; r++) {
                    float ea = exp2f(sA[nb][r] * scale2 - FM);
                    float eb = exp2f(sB[nb][r] * scale2 - FM);
                    pa[r] = (k0 + r <= qrA) ? ea : 0.f;
                    pb[r] = (k0 + r <= qrB) ? eb : 0.f;
                }
                uint2 ua, ub;
                ua.x = cvtpk(pa[0], pa[1]); ua.y = cvtpk(pa[2], pa[3]);
                ub.x = cvtpk(pb[0], pb[1]); ub.y = cvtpk(pb[2], pb[3]);
                *(uint2*)(pA_s[w] + l15 * LDP + nb * 16 + quad * 4) = ua;
                *(uint2*)(pB_s[w] + l15 * LDP + nb * 16 + quad * 4) = ub;
            }
            if (j < tB) { WAITV4; } else { WAITV0; }   // V(j) landed
            BAR();                                      // publish V
#pragma unroll
            for (int kc = 0; kc < 2; kc++) {
                bf16x8 pa = *(const bf16x8*)(pA_s[w] + l15 * LDP + kc * 32 + quad * 8);
                bf16x8 pb = *(const bf16x8*)(pB_s[w] + l15 * LDP + kc * 32 + quad * 8);
                lA = mfma16(pa, ones, lA);
                lB = mfma16(pb, ones, lB);
#pragma unroll
                for (int db = 0; db < 8; db++) {
                    int cc_s = (kc * 4 + quad) ^ xorv;
                    bf16x8 vf = *(const bf16x8*)(vt_s + (db * 16 + l15) * 64 + cc_s * 8);
                    oA[db] = mfma16(pa, vf, oA[db]);
                    oB[db] = mfma16(pb, vf, oB[db]);
                }
            }
        } else {
#pragma unroll
            for (int kc = 0; kc < 4; kc++) {
#pragma unroll
                for (int nb = 0; nb < 4; nb++) {
                    int cc_s = (kc * 4 + quad) ^ xorv;
                    bf16x8 kf = *(const bf16x8*)(ks + (nb * 16 + l15) * 128 + cc_s * 8);
                    sB[nb] = mfma16(kf, qb[kc], sB[nb]);   // swapped: S^T
                }
            }
#pragma unroll
            for (int nb = 0; nb < 4; nb++) {
                int k0 = kb + nb * 16 + quad * 4;
                float pb[4];
#pragma unroll
                for (int r = 0; r < 4; r++) {
                    float eb = exp2f(sB[nb][r] * scale2 - FM);
                    pb[r] = (k0 + r <= qrB) ? eb : 0.f;
                }
                uint2 ub;
                ub.x = cvtpk(pb[0], pb[1]); ub.y = cvtpk(pb[2], pb[3]);
                *(uint2*)(pB_s[w] + l15 * LDP + nb * 16 + quad * 4) = ub;
            }
            if (j < tB) { WAITV4; } else { WAITV0; }   // V(j) landed
            BAR();                                      // publish V
#pragma unroll
            for (int kc = 0; kc < 2; kc++) {
                bf16x8 pb = *(const bf16x8*)(pB_s[w] + l15 * LDP + kc * 32 + quad * 8);
                lB = mfma16(pb, ones, lB);
#pragma unroll
                for (int db = 0; db < 8; db++) {
                    int cc_s = (kc * 4 + quad) ^ xorv;
                    bf16x8 vf = *(const bf16x8*)(vt_s + (db * 16 + l15) * 64 + cc_s * 8);
                    oB[db] = mfma16(pb, vf, oB[db]);
                }
            }
        }
        BAR();   // p and v consumed -> reusable next iter
    }

    // epilogue: aout[b*S + s][h*128 + d] (bf16)
    const int b = bh >> 4;
    const int h = bh & 15;
    float invA[4], invB[4];
#pragma unroll
    for (int r = 0; r < 4; r++) { invA[r] = 1.f / lA[r]; invB[r] = 1.f / lB[r]; }
#pragma unroll
    for (int db = 0; db < 8; db++) {
#pragma unroll
        for (int r = 0; r < 4; r++) {
            int sA_row = qA + w * 16 + quad * 4 + r;
            int sB_row = qB + w * 16 + quad * 4 + r;
            size_t offA = ((size_t)(b * SS + sA_row)) * HID + h * DHEAD + db * 16 + l15;
            size_t offB = ((size_t)(b * SS + sB_row)) * HID + h * DHEAD + db * 16 + l15;
            aout[offA] = f2bf(oA[db][r] * invA[r]);
            aout[offB] = f2bf(oB[db][r] * invB[r]);
        }
    }
}

// ---------------------------------------------------------------------------
extern "C" void kernel_launch(void* const* d_in, const int* in_sizes, int n_in,
                              void* d_out, int out_size, void* d_ws, size_t ws_size,
                              hipStream_t stream)
{
    const float* X    = (const float*)d_in[0];
    const float* Wqkv = (const float*)d_in[1];
    const float* bqkv = (const float*)d_in[2];
    const float* Wd   = (const float*)d_in[3];
    const float* bd   = (const float*)d_in[4];
    float* out = (float*)d_out;

    char* ws = (char*)d_ws;
    const size_t MB = 1048576;
    ushort_t* qws  = (ushort_t*)(ws);              // 16 MiB [B,H,S,D] bf16
    ushort_t* kws  = (ushort_t*)(ws + 16 * MB);    // 16 MiB
    ushort_t* vtws = (ushort_t*)(ws + 32 * MB);    // 16 MiB [B,H,D,S]
    ushort_t* aout = (ushort_t*)(ws + 48 * MB);    // 16 MiB [B*S,HID] (aliases Xbf)
    ushort_t* Xbf  = (ushort_t*)(ws + 48 * MB);    // dead after qkv; aout reuses
    ushort_t* Wqbf = (ushort_t*)(ws + 64 * MB);    // 24 MiB
    ushort_t* Wdbf = (ushort_t*)(ws + 88 * MB);    // 8 MiB

    const int nX = MM * HID / 8, nWq = NQKV * HID / 8, nWd = HID * HID / 8;
    cvt3_kernel<<<(nX + nWq + nWd + 255) / 256, 256, 0, stream>>>(
        X, Xbf, nX, Wqkv, Wqbf, nWq, Wd, Wdbf, nWd);

    qkv_gemm_fast<<<dim3(NQKV / BN, MM / BM), 512, 0, stream>>>(Xbf, Wqbf, bqkv, qws, kws, vtws);
    rope_kernel3<<<(SS * 8 * 8) / 256, 256, 0, stream>>>(qws, kws);
    attn_kernel7<<<dim3(NT / 2 * BB * NHEAD), 256, 0, stream>>>(qws, kws, vtws, aout);
    dense_gemm_fast<<<dim3(HID / BN, MM / BM), 512, 0, stream>>>(aout, Wdbf, bd, out);
}

// Round 7
// 361.594 us; speedup vs baseline: 1.0687x; 1.0291x over previous
//
#include <hip/hip_runtime.h>
#include <hip/hip_bf16.h>
#include <stdint.h>

#define HID 2048
#define NHEAD 16
#define DHEAD 128
#define BB 2
#define SS 2048
#define MM (BB*SS)       // 4096
#define NQKV (3*HID)     // 6144
#define NT (SS/64)       // 32 k-tiles / q-tiles per head

typedef __attribute__((ext_vector_type(8))) short bf16x8;
typedef __attribute__((ext_vector_type(4))) float f32x4;
typedef unsigned short ushort_t;

__device__ __forceinline__ f32x4 mfma16(bf16x8 a, bf16x8 b, f32x4 c) {
    return __builtin_amdgcn_mfma_f32_16x16x32_bf16(a, b, c, 0, 0, 0);
}

__device__ __forceinline__ float bf2f(ushort_t u) {
    unsigned int x = ((unsigned int)u) << 16;
    return __builtin_bit_cast(float, x);
}
__device__ __forceinline__ ushort_t f2bf(float f) {
    unsigned int x = __builtin_bit_cast(unsigned int, f);
    unsigned int r = (x + 0x7FFFu + ((x >> 16) & 1u)) >> 16;
    return (ushort_t)r;
}

// packed f32x2 -> bf16x2 (RNE), one instruction; no builtin on gfx950 (m240)
__device__ __forceinline__ unsigned int cvtpk(float lo, float hi) {
    unsigned int r;
    asm volatile("v_cvt_pk_bf16_f32 %0, %1, %2" : "=v"(r) : "v"(lo), "v"(hi));
    return r;
}

__device__ __forceinline__ void cvt8(const float* __restrict__ g, ushort_t* l) {
    float4 a = *(const float4*)g;
    float4 b = *(const float4*)(g + 4);
    union { ushort_t u[8]; uint4 v; } t;
    t.u[0] = f2bf(a.x); t.u[1] = f2bf(a.y); t.u[2] = f2bf(a.z); t.u[3] = f2bf(a.w);
    t.u[4] = f2bf(b.x); t.u[5] = f2bf(b.y); t.u[6] = f2bf(b.z); t.u[7] = f2bf(b.w);
    *(uint4*)l = t.v;
}

// async global->LDS, 16 bytes per lane; LDS base wave-uniform, HW adds lane*16
__device__ __forceinline__ void gload16(const ushort_t* g, ushort_t* l) {
    __builtin_amdgcn_global_load_lds(
        (const __attribute__((address_space(1))) unsigned int*)(const void*)g,
        (__attribute__((address_space(3))) unsigned int*)(void*)l,
        16, 0, 0);
}

#define WAITV0 asm volatile("s_waitcnt vmcnt(0)" ::: "memory")
#define WAITV4 asm volatile("s_waitcnt vmcnt(4)" ::: "memory")
#define WAITV6 asm volatile("s_waitcnt vmcnt(6)" ::: "memory")
#define BAR()  __builtin_amdgcn_s_barrier()

// ---------------------------------------------------------------------------
// f32 -> bf16 bulk convert, all three tensors in one launch
// ---------------------------------------------------------------------------
__global__ void cvt3_kernel(const float* __restrict__ a, ushort_t* __restrict__ da, int na,
                            const float* __restrict__ b, ushort_t* __restrict__ db, int nb,
                            const float* __restrict__ c, ushort_t* __restrict__ dc, int nc)
{
    int i = blockIdx.x * blockDim.x + threadIdx.x;
    if (i < na) {
        cvt8(a + (size_t)i * 8, da + (size_t)i * 8);
    } else if (i < na + nb) {
        int j = i - na;
        cvt8(b + (size_t)j * 8, db + (size_t)j * 8);
    } else if (i < na + nb + nc) {
        int j = i - na - nb;
        cvt8(c + (size_t)j * 8, dc + (size_t)j * 8);
    }
}

// ---------------------------------------------------------------------------
// QKV GEMM (round-1 proven core): BM=256, BN=128, BK=64, 512 thr = 8 waves,
// 3 rotating LDS buffers, counted vmcnt(6), T2 swizzle, T5 setprio.
// For V blocks (n0 >= 4096) MFMA operands SWAPPED so acc holds C^T.
// ---------------------------------------------------------------------------
#define BM 256
#define BN 128
#define BKK 64
#define NTK (HID/BKK)         // 32
#define ASZ (BM*BKK)          // 16384 ushorts (32 KiB)
#define BSZ (BN*BKK)          // 8192 ushorts (16 KiB)
#define BUFSZ (ASZ+BSZ)       // 24576 ushorts (48 KiB)

__global__ __launch_bounds__(512, 1) void qkv_gemm_fast(
    const ushort_t* __restrict__ X,
    const ushort_t* __restrict__ W,
    const float* __restrict__ bias,
    ushort_t* __restrict__ qws,
    ushort_t* __restrict__ kws,
    ushort_t* __restrict__ vtws)
{
    __shared__ __align__(16) ushort_t smem[3 * BUFSZ];   // 144 KiB

    const int tid  = threadIdx.x;
    const int lane = tid & 63;
    const int w    = tid >> 6;            // 0..7
    const int wm   = w >> 1, wn = w & 1;
    const int quad = lane >> 4;
    const int l15  = lane & 15;
    const int sub  = (lane & 7) ^ (lane >> 3);   // inverse-swizzled src chunk
    const int rloc = lane >> 3;                  // row within 8-row block
    const int m0 = blockIdx.y * BM;
    const int n0 = blockIdx.x * BN;
    const bool vmode = (n0 >= 2 * HID);

    const ushort_t* gA = X + (size_t)m0 * HID;
    const ushort_t* gB = W + (size_t)n0 * HID;

    f32x4 acc[4][4];
#pragma unroll
    for (int i = 0; i < 4; i++)
#pragma unroll
        for (int j = 0; j < 4; j++)
#pragma unroll
            for (int e = 0; e < 4; e++) acc[i][j][e] = 0.f;

    auto STAGE = [&](int bufi, int t) {
        ushort_t* lA = smem + bufi * BUFSZ;
        ushort_t* lB = lA + ASZ;
        const ushort_t* ga = gA + t * BKK;
        const ushort_t* gb = gB + t * BKK;
#pragma unroll
        for (int i = 0; i < 4; i++) {
            int blk = w * 4 + i;                 // 0..31 -> A rows blk*8..+7
            gload16(ga + (size_t)(blk * 8 + rloc) * HID + sub * 8, lA + blk * 512);
        }
#pragma unroll
        for (int i = 0; i < 2; i++) {
            int blk = w * 2 + i;                 // 0..15 -> B rows blk*8..+7
            gload16(gb + (size_t)(blk * 8 + rloc) * HID + sub * 8, lB + blk * 512);
        }
    };

    auto COMPUTE = [&](int bufi) {
        const ushort_t* lA = smem + bufi * BUFSZ;
        const ushort_t* lB = lA + ASZ;
        bf16x8 af[2][4], bfr[2][4];
#pragma unroll
        for (int kk = 0; kk < 2; kk++) {
            const int cs = ((kk * 4 + quad) ^ (l15 & 7)) << 3;   // swizzled chunk
#pragma unroll
            for (int mb = 0; mb < 4; mb++)
                af[kk][mb] = *(const bf16x8*)(lA + (wm * 64 + mb * 16 + l15) * 64 + cs);
#pragma unroll
            for (int nb = 0; nb < 4; nb++)
                bfr[kk][nb] = *(const bf16x8*)(lB + (wn * 64 + nb * 16 + l15) * 64 + cs);
        }
        __builtin_amdgcn_s_setprio(1);
        if (!vmode) {
#pragma unroll
            for (int kk = 0; kk < 2; kk++)
#pragma unroll
                for (int mb = 0; mb < 4; mb++)
#pragma unroll
                    for (int nb = 0; nb < 4; nb++)
                        acc[mb][nb] = mfma16(af[kk][mb], bfr[kk][nb], acc[mb][nb]);
        } else {
#pragma unroll
            for (int kk = 0; kk < 2; kk++)
#pragma unroll
                for (int mb = 0; mb < 4; mb++)
#pragma unroll
                    for (int nb = 0; nb < 4; nb++)
                        acc[mb][nb] = mfma16(bfr[kk][nb], af[kk][mb], acc[mb][nb]);  // D = C^T
        }
        __builtin_amdgcn_s_setprio(0);
    };

    // prologue: stage t0, t1; wait t0 (6 oldest of 12), publish
    STAGE(0, 0);
    STAGE(1, 1);
    WAITV6;
    BAR();

    int buf = 0;
    for (int t = 0; t < NTK - 2; t++) {
        int b2 = buf + 2; if (b2 >= 3) b2 -= 3;
        STAGE(b2, t + 2);
        COMPUTE(buf);
        WAITV6;                 // t+1 done, t+2 in flight
        BAR();
        buf++; if (buf == 3) buf = 0;
    }
    // tail: t = NTK-2, NTK-1
    COMPUTE(buf);
    WAITV0;
    BAR();
    buf++; if (buf == 3) buf = 0;
    COMPUTE(buf);

    // epilogue
    if (!vmode) {
#pragma unroll
        for (int nb = 0; nb < 4; nb++) {
            int n = n0 + wn * 64 + nb * 16 + l15;
            float bv = bias[n];
            int mat = n >> 11;        // 0=q, 1=k
            int h   = (n >> 7) & 15;
            int d   = n & 127;
            ushort_t* dst = (mat == 0) ? qws : kws;
#pragma unroll
            for (int mb = 0; mb < 4; mb++) {
#pragma unroll
                for (int r = 0; r < 4; r++) {
                    int m = m0 + wm * 64 + mb * 16 + quad * 4 + r;
                    int b = m >> 11;
                    int s = m & 2047;
                    dst[(((size_t)(b * 16 + h) * SS) + s) * DHEAD + d] =
                        f2bf(acc[mb][nb][r] + bv);
                }
            }
        }
    } else {
        const int b = m0 >> 11;
#pragma unroll
        for (int nb = 0; nb < 4; nb++) {
#pragma unroll
            for (int r = 0; r < 4; r++) {
                int n = n0 + wn * 64 + nb * 16 + quad * 4 + r;
                float bv = bias[n];
                int h = (n >> 7) & 15;
                int d = n & 127;
#pragma unroll
                for (int mb = 0; mb < 4; mb++) {
                    int s = (m0 & 2047) + wm * 64 + mb * 16 + l15;
                    vtws[(((size_t)(b * 16 + h) * DHEAD) + d) * SS + s] =
                        f2bf(acc[mb][nb][r] + bv);
                }
            }
        }
    }
}

// ---------------------------------------------------------------------------
// Dense GEMM — round-1 pipelined core (unchanged).
// ---------------------------------------------------------------------------
__global__ __launch_bounds__(512, 1) void dense_gemm_fast(
    const ushort_t* __restrict__ A,
    const ushort_t* __restrict__ W,
    const float* __restrict__ bias,
    float* __restrict__ out)
{
    __shared__ __align__(16) ushort_t smem[3 * BUFSZ];   // 144 KiB

    const int tid  = threadIdx.x;
    const int lane = tid & 63;
    const int w    = tid >> 6;
    const int wm   = w >> 1;
    const int wn   = w & 1;
    const int quad = lane >> 4;
    const int l15  = lane & 15;
    const int sub  = (lane & 7) ^ (lane >> 3);
    const int rloc = lane >> 3;
    const int m0 = blockIdx.y * BM;
    const int n0 = blockIdx.x * BN;

    const ushort_t* gA = A + (size_t)m0 * HID;
    const ushort_t* gB = W + (size_t)n0 * HID;

    f32x4 acc[4][4];
#pragma unroll
    for (int i = 0; i < 4; i++)
#pragma unroll
        for (int j = 0; j < 4; j++)
#pragma unroll
            for (int e = 0; e < 4; e++) acc[i][j][e] = 0.f;

    auto STAGE = [&](int bufi, int t) {
        ushort_t* lA = smem + bufi * BUFSZ;
        ushort_t* lB = lA + ASZ;
        const ushort_t* ga = gA + t * BKK;
        const ushort_t* gb = gB + t * BKK;
#pragma unroll
        for (int i = 0; i < 4; i++) {
            int blk = w * 4 + i;
            gload16(ga + (size_t)(blk * 8 + rloc) * HID + sub * 8, lA + blk * 512);
        }
#pragma unroll
        for (int i = 0; i < 2; i++) {
            int blk = w * 2 + i;
            gload16(gb + (size_t)(blk * 8 + rloc) * HID + sub * 8, lB + blk * 512);
        }
    };

    auto COMPUTE = [&](int bufi) {
        const ushort_t* lA = smem + bufi * BUFSZ;
        const ushort_t* lB = lA + ASZ;
        bf16x8 af[2][4], bfr[2][4];
#pragma unroll
        for (int kk = 0; kk < 2; kk++) {
            const int cs = ((kk * 4 + quad) ^ (l15 & 7)) << 3;
#pragma unroll
            for (int mb = 0; mb < 4; mb++)
                af[kk][mb] = *(const bf16x8*)(lA + (wm * 64 + mb * 16 + l15) * 64 + cs);
#pragma unroll
            for (int nb = 0; nb < 4; nb++)
                bfr[kk][nb] = *(const bf16x8*)(lB + (wn * 64 + nb * 16 + l15) * 64 + cs);
        }
        __builtin_amdgcn_s_setprio(1);
#pragma unroll
        for (int kk = 0; kk < 2; kk++)
#pragma unroll
            for (int mb = 0; mb < 4; mb++)
#pragma unroll
                for (int nb = 0; nb < 4; nb++)
                    acc[mb][nb] = mfma16(af[kk][mb], bfr[kk][nb], acc[mb][nb]);
        __builtin_amdgcn_s_setprio(0);
    };

    STAGE(0, 0);
    STAGE(1, 1);
    WAITV6;
    BAR();

    int buf = 0;
    for (int t = 0; t < NTK - 2; t++) {
        int b2 = buf + 2; if (b2 >= 3) b2 -= 3;
        STAGE(b2, t + 2);
        COMPUTE(buf);
        WAITV6;
        BAR();
        buf++; if (buf == 3) buf = 0;
    }
    COMPUTE(buf);
    WAITV0;
    BAR();
    buf++; if (buf == 3) buf = 0;
    COMPUTE(buf);

#pragma unroll
    for (int nb = 0; nb < 4; nb++) {
        int n = n0 + wn * 64 + nb * 16 + l15;
        float bv = bias[n];
#pragma unroll
        for (int mb = 0; mb < 4; mb++) {
#pragma unroll
            for (int r = 0; r < 4; r++) {
                int m = m0 + wm * 64 + mb * 16 + quad * 4 + r;
                out[(size_t)m * HID + n] = acc[mb][nb][r] + bv;
            }
        }
    }
}

// ---------------------------------------------------------------------------
// RoPE: vectorized (uint4 = 8 bf16 per access).  thread = (bh-group, s, d2g);
// each thread rotates 8 (d2, d2+64) pairs for 4 heads.
// ---------------------------------------------------------------------------
__global__ void rope_kernel3(ushort_t* __restrict__ qws, ushort_t* __restrict__ kws)
{
    int t = blockIdx.x * blockDim.x + threadIdx.x;   // 131072 threads
    int d2g = t & 7;
    int s   = (t >> 3) & 2047;
    int bh0 = (t >> 14) * 4;                          // 0..28 step 4

    float sn[8], cs[8];
#pragma unroll
    for (int jj = 0; jj < 8; jj++) {
        int d2 = d2g * 8 + jj;
        float inv_freq = exp2f(-(float)d2 * (13.287712379549449f / 64.f));
        float fr = (float)s * inv_freq;
        sincosf(fr, &sn[jj], &cs[jj]);
    }

    size_t base0 = (size_t)s * DHEAD + d2g * 8;
#pragma unroll
    for (int q = 0; q < 4; q++) {
        size_t base = base0 + (size_t)(bh0 + q) * (SS * DHEAD);
        {
            union { ushort_t u[8]; uint4 v; } x1, x2, y1, y2;
            x1.v = *(const uint4*)(qws + base);
            x2.v = *(const uint4*)(qws + base + 64);
#pragma unroll
            for (int jj = 0; jj < 8; jj++) {
                float a = bf2f(x1.u[jj]), b = bf2f(x2.u[jj]);
                y1.u[jj] = f2bf(a * cs[jj] - b * sn[jj]);
                y2.u[jj] = f2bf(b * cs[jj] + a * sn[jj]);
            }
            *(uint4*)(qws + base) = y1.v;
            *(uint4*)(qws + base + 64) = y2.v;
        }
        {
            union { ushort_t u[8]; uint4 v; } x1, x2, y1, y2;
            x1.v = *(const uint4*)(kws + base);
            x2.v = *(const uint4*)(kws + base + 64);
#pragma unroll
            for (int jj = 0; jj < 8; jj++) {
                float a = bf2f(x1.u[jj]), b = bf2f(x2.u[jj]);
                y1.u[jj] = f2bf(a * cs[jj] - b * sn[jj]);
                y2.u[jj] = f2bf(b * cs[jj] + a * sn[jj]);
            }
            *(uint4*)(kws + base) = y1.v;
            *(uint4*)(kws + base + 64) = y2.v;
        }
    }
}

// ---------------------------------------------------------------------------
// Causal flash attention v8: r6's verified math (swapped QK^T, cvt_pk P-path,
// paired q-tiles, XCD pinning) restructured into a 1-barrier/iter software
// pipeline:
//   phase j: issue V(j+1),K(j+2) -> PV(j) ++ QK(j+1) (independent MFMA
//   streams, ~68 MFMA unbroken) -> softmax(j+1)->P -> vmcnt(0) (loads had the
//   whole phase in flight) -> BAR.
// K and V double-buffered (stage K(j+2)->kslot[j&1]: last read phase j-1,
// all readers behind the barrier -> race-free).  P single-buffered and
// wave-private: PV(j) P-reads precede QK(j+1) P-writes in program order (same
// region -> order preserved); no P barrier.  P uses LDP=64 + 16B-granule XOR
// swizzle (h ^= l15&7, write & read identical) for bank stagger at zero pad,
// keeping LDS = 32(K)+32(V)+16(P) = 80 KiB exactly -> 2 blocks/CU retained.
// ---------------------------------------------------------------------------
__global__ __launch_bounds__(256, 2) void attn_kernel8(
    const ushort_t* __restrict__ qws,
    const ushort_t* __restrict__ kws,
    const ushort_t* __restrict__ vtws,
    ushort_t* __restrict__ aout)
{
    __shared__ __align__(16) ushort_t k_s[2][64 * 128];   // 32 KiB, swizzled
    __shared__ __align__(16) ushort_t vt_s[2][128 * 64];  // 32 KiB, swizzled
    __shared__ __align__(16) ushort_t pA_s[4][16 * 64];   // 8 KiB, XOR-swizzled
    __shared__ __align__(16) ushort_t pB_s[4][16 * 64];   // 8 KiB

    const int tid  = threadIdx.x;
    const int lane = tid & 63;
    const int w    = tid >> 6;
    const int quad = lane >> 4;
    const int l15  = lane & 15;

    const int g  = blockIdx.x;                       // 0..511
    const int bh = (g & 7) | (((g >> 3) & 3) << 3);  // head pinned to XCD g%8
    const int tA = g >> 5;                           // 0..15
    const int tB = NT - 1 - tA;                      // 31..16
    const int qA = tA * 64, qB = tB * 64;
    const size_t qk_base = (size_t)bh * SS * DHEAD;

    // Q fragments in registers
    bf16x8 qa[4], qb[4];
    {
        const ushort_t* rowA = qws + qk_base + (size_t)(qA + w * 16 + l15) * DHEAD;
        const ushort_t* rowB = qws + qk_base + (size_t)(qB + w * 16 + l15) * DHEAD;
#pragma unroll
        for (int kc = 0; kc < 4; kc++) {
            qa[kc] = *(const bf16x8*)(rowA + kc * 32 + quad * 8);
            qb[kc] = *(const bf16x8*)(rowB + kc * 32 + quad * 8);
        }
    }

    // ones B-fragment (bf16 1.0 = 0x3F80)
    bf16x8 ones;
#pragma unroll
    for (int i = 0; i < 8; i++) ones[i] = (short)0x3F80;

    f32x4 oA[8], oB[8], lA, lB;
#pragma unroll
    for (int i = 0; i < 8; i++)
#pragma unroll
        for (int e = 0; e < 4; e++) { oA[i][e] = 0.f; oB[i][e] = 0.f; }
#pragma unroll
    for (int e = 0; e < 4; e++) { lA[e] = 0.f; lB[e] = 0.f; }

    const int srowK = lane >> 4;
    const int srowV = lane >> 3;
    const int ccgV  = (lane & 7) ^ (lane >> 3);

    // swapped layout: q = l15 per lane, k = kb + nb*16 + quad*4 + r
    const int qrA = qA + w * 16 + l15;
    const int qrB = qB + w * 16 + l15;
    const int xorv = l15 & 7;
    const int pxor = l15 & 7;   // P-granule XOR (16B units)

    const float scale2 = 0.12753102015727466f;  // (1/sqrt(128)) * log2(e)
    const float FM = 16.0f;                     // fixed softmax max (exp2 domain)

    auto KSTAGE = [&](int j, int slot) {
        const int kb = j * 64;
#pragma unroll
        for (int i = 0; i < 4; i++) {
            int P = i * 4 + w;
            int row = P * 4 + srowK;
            int ccg = l15 ^ (((P & 1) * 4) + srowK);
            gload16(kws + qk_base + (size_t)(kb + row) * DHEAD + ccg * 8,
                    k_s[slot] + P * 512);
        }
    };
    auto VSTAGE = [&](int j, int slot) {
        const int kb = j * 64;
#pragma unroll
        for (int i = 0; i < 4; i++) {
            int P = i * 4 + w;
            int row = P * 8 + srowV;
            gload16(vtws + qk_base + (size_t)row * SS + kb + ccgV * 8,
                    vt_s[slot] + P * 512);
        }
    };

    // QK^T (swapped) + softmax + packed P-write for tile jj (K from k_s[jj&1])
    auto QKSM = [&](int jj) {
        const int kb = jj * 64;
        const ushort_t* ks = k_s[jj & 1];
        f32x4 sA[4], sB[4];
#pragma unroll
        for (int nb = 0; nb < 4; nb++)
#pragma unroll
            for (int e = 0; e < 4; e++) { sA[nb][e] = 0.f; sB[nb][e] = 0.f; }

        if (jj <= tA) {
#pragma unroll
            for (int kc = 0; kc < 4; kc++) {
#pragma unroll
                for (int nb = 0; nb < 4; nb++) {
                    int cc_s = (kc * 4 + quad) ^ xorv;
                    bf16x8 kf = *(const bf16x8*)(ks + (nb * 16 + l15) * 128 + cc_s * 8);
                    sA[nb] = mfma16(kf, qa[kc], sA[nb]);   // swapped: S^T
                    sB[nb] = mfma16(kf, qb[kc], sB[nb]);
                }
            }
#pragma unroll
            for (int nb = 0; nb < 4; nb++) {
                int k0 = kb + nb * 16 + quad * 4;
                float pa[4], pb[4];
#pragma unroll
                for (int r = 0; r < 4; r++) {
                    float ea = exp2f(sA[nb][r] * scale2 - FM);
                    float eb = exp2f(sB[nb][r] * scale2 - FM);
                    pa[r] = (k0 + r <= qrA) ? ea : 0.f;
                    pb[r] = (k0 + r <= qrB) ? eb : 0.f;
                }
                uint2 ua, ub;
                ua.x = cvtpk(pa[0], pa[1]); ua.y = cvtpk(pa[2], pa[3]);
                ub.x = cvtpk(pb[0], pb[1]); ub.y = cvtpk(pb[2], pb[3]);
                int hs = ((nb * 2 + (quad >> 1)) ^ pxor) * 8 + (quad & 1) * 4;
                *(uint2*)(pA_s[w] + l15 * 64 + hs) = ua;
                *(uint2*)(pB_s[w] + l15 * 64 + hs) = ub;
            }
        } else {
#pragma unroll
            for (int kc = 0; kc < 4; kc++) {
#pragma unroll
                for (int nb = 0; nb < 4; nb++) {
                    int cc_s = (kc * 4 + quad) ^ xorv;
                    bf16x8 kf = *(const bf16x8*)(ks + (nb * 16 + l15) * 128 + cc_s * 8);
                    sB[nb] = mfma16(kf, qb[kc], sB[nb]);   // swapped: S^T
                }
            }
#pragma unroll
            for (int nb = 0; nb < 4; nb++) {
                int k0 = kb + nb * 16 + quad * 4;
                float pb[4];
#pragma unroll
                for (int r = 0; r < 4; r++) {
                    float eb = exp2f(sB[nb][r] * scale2 - FM);
                    pb[r] = (k0 + r <= qrB) ? eb : 0.f;
                }
                uint2 ub;
                ub.x = cvtpk(pb[0], pb[1]); ub.y = cvtpk(pb[2], pb[3]);
                int hs = ((nb * 2 + (quad >> 1)) ^ pxor) * 8 + (quad & 1) * 4;
                *(uint2*)(pB_s[w] + l15 * 64 + hs) = ub;
            }
        }
    };

    // PV for tile jj (V from vt_s[jj&1], P from wave-private buffers)
    auto PV = [&](int jj) {
        const ushort_t* vs = vt_s[jj & 1];
        const bool dual = (jj <= tA);
#pragma unroll
        for (int kc = 0; kc < 2; kc++) {
            int hp = ((kc * 4 + quad) ^ pxor) * 8;
            bf16x8 pb = *(const bf16x8*)(pB_s[w] + l15 * 64 + hp);
            lB = mfma16(pb, ones, lB);
            if (dual) {
                bf16x8 pa = *(const bf16x8*)(pA_s[w] + l15 * 64 + hp);
                lA = mfma16(pa, ones, lA);
#pragma unroll
                for (int db = 0; db < 8; db++) {
                    int cc_s = (kc * 4 + quad) ^ xorv;
                    bf16x8 vf = *(const bf16x8*)(vs + (db * 16 + l15) * 64 + cc_s * 8);
                    oA[db] = mfma16(pa, vf, oA[db]);
                    oB[db] = mfma16(pb, vf, oB[db]);
                }
            } else {
#pragma unroll
                for (int db = 0; db < 8; db++) {
                    int cc_s = (kc * 4 + quad) ^ xorv;
                    bf16x8 vf = *(const bf16x8*)(vs + (db * 16 + l15) * 64 + cc_s * 8);
                    oB[db] = mfma16(pb, vf, oB[db]);
                }
            }
        }
    };

    // prologue: K(0), V(0), K(1) staged; compute P(0)
    KSTAGE(0, 0);
    VSTAGE(0, 0);
    KSTAGE(1, 1);
    WAITV4;          // K(0), V(0) landed; K(1) in flight
    BAR();
    QKSM(0);
    WAITV0;          // K(1) landed
    BAR();

    // main pipeline: one barrier per iteration
    for (int j = 0; j <= tB; j++) {
        if (j + 1 <= tB) VSTAGE(j + 1, (j + 1) & 1);
        if (j + 2 <= tB) KSTAGE(j + 2, j & 1);
        PV(j);                        // reads P(j), V(j)
        if (j + 1 <= tB) QKSM(j + 1); // computes + writes P(j+1) (after P(j) reads)
        WAITV0;                       // staged loads had the whole phase in flight
        BAR();
    }

    // epilogue: aout[b*S + s][h*128 + d] (bf16)
    const int b = bh >> 4;
    const int h = bh & 15;
    float invA[4], invB[4];
#pragma unroll
    for (int r = 0; r < 4; r++) { invA[r] = 1.f / lA[r]; invB[r] = 1.f / lB[r]; }
#pragma unroll
    for (int db = 0; db < 8; db++) {
#pragma unroll
        for (int r = 0; r < 4; r++) {
            int sA_row = qA + w * 16 + quad * 4 + r;
            int sB_row = qB + w * 16 + quad * 4 + r;
            size_t offA = ((size_t)(b * SS + sA_row)) * HID + h * DHEAD + db * 16 + l15;
            size_t offB = ((size_t)(b * SS + sB_row)) * HID + h * DHEAD + db * 16 + l15;
            aout[offA] = f2bf(oA[db][r] * invA[r]);
            aout[offB] = f2bf(oB[db][r] * invB[r]);
        }
    }
}

// ---------------------------------------------------------------------------
extern "C" void kernel_launch(void* const* d_in, const int* in_sizes, int n_in,
                              void* d_out, int out_size, void* d_ws, size_t ws_size,
                              hipStream_t stream)
{
    const float* X    = (const float*)d_in[0];
    const float* Wqkv = (const float*)d_in[1];
    const float* bqkv = (const float*)d_in[2];
    const float* Wd   = (const float*)d_in[3];
    const float* bd   = (const float*)d_in[4];
    float* out = (float*)d_out;

    char* ws = (char*)d_ws;
    const size_t MB = 1048576;
    ushort_t* qws  = (ushort_t*)(ws);              // 16 MiB [B,H,S,D] bf16
    ushort_t* kws  = (ushort_t*)(ws + 16 * MB);    // 16 MiB
    ushort_t* vtws = (ushort_t*)(ws + 32 * MB);    // 16 MiB [B,H,D,S]
    ushort_t* aout = (ushort_t*)(ws + 48 * MB);    // 16 MiB [B*S,HID] (aliases Xbf)
    ushort_t* Xbf  = (ushort_t*)(ws + 48 * MB);    // dead after qkv; aout reuses
    ushort_t* Wqbf = (ushort_t*)(ws + 64 * MB);    // 24 MiB
    ushort_t* Wdbf = (ushort_t*)(ws + 88 * MB);    // 8 MiB

    const int nX = MM * HID / 8, nWq = NQKV * HID / 8, nWd = HID * HID / 8;
    cvt3_kernel<<<(nX + nWq + nWd + 255) / 256, 256, 0, stream>>>(
        X, Xbf, nX, Wqkv, Wqbf, nWq, Wd, Wdbf, nWd);

    qkv_gemm_fast<<<dim3(NQKV / BN, MM / BM), 512, 0, stream>>>(Xbf, Wqbf, bqkv, qws, kws, vtws);
    rope_kernel3<<<(SS * 8 * 8) / 256, 256, 0, stream>>>(qws, kws);
    attn_kernel8<<<dim3(NT / 2 * BB * NHEAD), 256, 0, stream>>>(qws, kws, vtws, aout);
    dense_gemm_fast<<<dim3(HID / BN, MM / BM), 512, 0, stream>>>(aout, Wdbf, bd, out);
}